// Round 4
// baseline (355.447 us; speedup 1.0000x reference)
//
#include <hip/hip_runtime.h>

typedef long long i64;
typedef __attribute__((ext_vector_type(8))) short short8;   // 8 bf16 = 4 VGPRs (MFMA A/B frag)
typedef __attribute__((ext_vector_type(4))) float float4v;  // MFMA C/D frag

#define NB   131072
#define RPB  32          // rows per block
#define NAUX 16
#define ASTR 48          // LDS A-plane row stride in bf16 elems (96 B, 16B-aligned rows)

__device__ __forceinline__ unsigned short f2bf(float f) {   // f32 -> bf16 (RN)
    union { float f; unsigned u; } c; c.f = f;
    return (unsigned short)((c.u + 0x7fffu + ((c.u >> 16) & 1u)) >> 16);
}
__device__ __forceinline__ float bf2f(unsigned short h) {
    union { float f; unsigned u; } c; c.u = ((unsigned)h) << 16; return c.f;
}

__global__ __launch_bounds__(256) void mote_kernel(
    const float* __restrict__ timestamp,
    const float* __restrict__ aux,
    const float* __restrict__ router_W,   // [17,4]
    const float* __restrict__ router_b,   // [4]
    const float* __restrict__ freqs,      // [16]
    const float* __restrict__ fourier_W,  // [32,128]
    const float* __restrict__ knots,      // [16]
    const float* __restrict__ spline_W,   // [16,128]
    const float* __restrict__ centers,    // [16]
    const float* __restrict__ gauss_W,    // [16,128]
    const float* __restrict__ wav_centers,// [16]
    const float* __restrict__ wav_scales, // [16]
    const float* __restrict__ wavelet_W,  // [16,128]
    float* __restrict__ out)
{
    const int tid  = threadIdx.x;
    const int wv   = tid >> 6;           // wave = expert
    const int lane = tid & 63;
    const int q    = lane >> 4;          // MFMA quad
    const int n    = lane & 15;          // MFMA col (B/C) / row (A)
    const i64 row0 = (i64)blockIdx.x * RPB;

    // A-planes: fourier hi/lo (k=0..31); packed [Ah(16)|Al(16)] for spline/gauss/wavelet
    __shared__ __attribute__((aligned(16))) unsigned short Af_h[RPB][ASTR];
    __shared__ __attribute__((aligned(16))) unsigned short Af_l[RPB][ASTR];
    __shared__ __attribute__((aligned(16))) unsigned short Ap[3][RPB][ASTR];
    __shared__ float disp[RPB][4];

    // ---- B-fragments: weights -> split-bf16 MFMA B-layout, register-resident ----
    // B[k][n']: lane holds k = q*8+j (K=16 experts: duplicated rows k&15), n' = ct*16+n
    short8 Bh[8], Bl[8];
    {
        const float* We = (wv == 0) ? fourier_W : (wv == 1) ? spline_W
                        : (wv == 2) ? gauss_W   : wavelet_W;
#pragma unroll
        for (int ct = 0; ct < 8; ++ct) {
#pragma unroll
            for (int j = 0; j < 8; ++j) {
                int k = q * 8 + j;
                if (wv != 0) k &= 15;                 // [Wh;Wh] / [Wl;Wl] duplication
                const float w = We[k * 128 + ct * 16 + n];
                const unsigned short h = f2bf(w);
                Bh[ct][j] = (short)h;
                Bl[ct][j] = (short)f2bf(w - bf2f(h));
            }
        }
    }

    // ---- phase 1: basis features -> split-bf16 A-planes in LDS (2560 vals, 10/thread) ----
#pragma unroll
    for (int it = 0; it < (RPB * 80) / 256; ++it) {
        const int v = tid + it * 256;
        const int r = v / 80;
        const int j = v - r * 80;
        const float t = timestamp[row0 + r];
        float val;
        if (j < 32) {
            const float tf = t * freqs[j & 15];
            val = (j < 16) ? __sinf(tf) : __cosf(tf);
        } else if (j < 48) {
            const float d = (t - knots[j - 32]) * 3.75f;     // 1/h, h = 4/15
            val = __expf(-d * d);
        } else if (j < 64) {
            const float d = t - centers[j - 48];
            val = __expf(-d * d);
        } else {
            const float u = (t - wav_centers[j - 64]) / wav_scales[j - 64];
            val = (1.0f - u * u) * __expf(-0.5f * u * u);
        }
        const unsigned short h = f2bf(val);
        const unsigned short l = f2bf(val - bf2f(h));
        if (j < 32) { Af_h[r][j] = h; Af_l[r][j] = l; }
        else {
            const int ee = (j - 32) >> 4;
            const int k  = (j - 32) & 15;
            Ap[ee][r][k]      = h;
            Ap[ee][r][k + 16] = l;
        }
    }

    // ---- phase 2: router (f64 rank to match numpy, f32 softmax), top-2 gate ----
    if (tid < RPB * 4) {
        const int r = tid >> 2, e = tid & 3;
        const i64 row = row0 + r;

        double acc = (double)timestamp[row] * (double)router_W[e];
        const float4* a4 = (const float4*)(aux + row * NAUX);
#pragma unroll
        for (int p = 0; p < 4; ++p) {
            const float4 a = a4[p];
            acc = fma((double)a.x, (double)router_W[(1 + 4 * p + 0) * 4 + e], acc);
            acc = fma((double)a.y, (double)router_W[(1 + 4 * p + 1) * 4 + e], acc);
            acc = fma((double)a.z, (double)router_W[(1 + 4 * p + 2) * 4 + e], acc);
            acc = fma((double)a.w, (double)router_W[(1 + 4 * p + 3) * 4 + e], acc);
        }
        acc += (double)router_b[e];

        const int lb = (tid & 63) & ~3;
        const double l0 = __shfl(acc, lb + 0, 64);
        const double l1 = __shfl(acc, lb + 1, 64);
        const double l2 = __shfl(acc, lb + 2, 64);
        const double l3 = __shfl(acc, lb + 3, 64);

        int rank = 0;
        rank += (l0 > acc) || (l0 == acc && 0 < e);
        rank += (l1 > acc) || (l1 == acc && 1 < e);
        rank += (l2 > acc) || (l2 == acc && 2 < e);
        rank += (l3 > acc) || (l3 == acc && 3 < e);
        const bool top = (rank < 2);

        const double m = fmax(fmax(l0, l1), fmax(l2, l3));
        const float x0 = __expf((float)(l0 - m));
        const float x1 = __expf((float)(l1 - m));
        const float x2 = __expf((float)(l2 - m));
        const float x3 = __expf((float)(l3 - m));
        const float we = __expf((float)(acc - m)) / (x0 + x1 + x2 + x3);

        disp[r][e] = top ? we : 0.0f;
        out[(i64)NB * 512 + row * 4 + e] = we;                    // raw_weights
        out[(i64)NB * 516 + row * 4 + e] = top ? 1.0f : 0.0f;     // mask
    }
    __syncthreads();

    // ---- phase 3: MFMA GEMM, exact split-bf16; wave owns its expert ----
    const unsigned short* Aplane = (wv == 0) ? &Af_h[0][0] : &Ap[wv - 1][0][0];
#pragma unroll
    for (int rt = 0; rt < 2; ++rt) {
        const int rbase = rt * 16;
        // A-frag: lane holds A[m = n][k = q*8 + j]
        const short8 a0 = *(const short8*)(Aplane + (rbase + n) * ASTR + q * 8);
        short8 a1{};
        if (wv == 0)
            a1 = *(const short8*)(&Af_l[0][0] + (rbase + n) * ASTR + q * 8);

        const float s0 = disp[rbase + q * 4 + 0][wv];
        const float s1 = disp[rbase + q * 4 + 1][wv];
        const float s2 = disp[rbase + q * 4 + 2][wv];
        const float s3 = disp[rbase + q * 4 + 3][wv];

#pragma unroll
        for (int ct = 0; ct < 8; ++ct) {
            float4v c = {0.0f, 0.0f, 0.0f, 0.0f};
            c = __builtin_amdgcn_mfma_f32_16x16x32_bf16(a0, Bh[ct], c, 0, 0, 0);
            if (wv == 0)   // fourier: + Al*Wh (K=16 experts get this via packed A)
                c = __builtin_amdgcn_mfma_f32_16x16x32_bf16(a1, Bh[ct], c, 0, 0, 0);
            c = __builtin_amdgcn_mfma_f32_16x16x32_bf16(a0, Bl[ct], c, 0, 0, 0);

            // C/D: col = n, row = q*4 + reg  [m89-verified layout]
            float* op = out + (row0 + rbase + q * 4) * 512 + wv * 128 + ct * 16 + n;
            __builtin_nontemporal_store(c[0] * s0, op);
            __builtin_nontemporal_store(c[1] * s1, op + 512);
            __builtin_nontemporal_store(c[2] * s2, op + 1024);
            __builtin_nontemporal_store(c[3] * s3, op + 1536);
        }
    }
}

extern "C" void kernel_launch(void* const* d_in, const int* in_sizes, int n_in,
                              void* d_out, int out_size, void* d_ws, size_t ws_size,
                              hipStream_t stream) {
    const float* timestamp   = (const float*)d_in[0];
    const float* aux         = (const float*)d_in[1];
    const float* router_W    = (const float*)d_in[2];
    const float* router_b    = (const float*)d_in[3];
    const float* freqs       = (const float*)d_in[4];
    const float* fourier_W   = (const float*)d_in[5];
    const float* knots       = (const float*)d_in[6];
    const float* spline_W    = (const float*)d_in[7];
    const float* centers     = (const float*)d_in[8];
    const float* gauss_W     = (const float*)d_in[9];
    const float* wav_centers = (const float*)d_in[10];
    const float* wav_scales  = (const float*)d_in[11];
    const float* wavelet_W   = (const float*)d_in[12];
    float* out = (float*)d_out;

    mote_kernel<<<NB / RPB, 256, 0, stream>>>(
        timestamp, aux, router_W, router_b, freqs, fourier_W, knots, spline_W,
        centers, gauss_W, wav_centers, wav_scales, wavelet_W, out);
}